// Round 6
// baseline (48.672 us; speedup 1.0000x reference)
//
#include <hip/hip_runtime.h>

// Problem constants (fixed by the reference).
#define BSZ    16      // batch
#define NN     1024    // tokens per batch
#define DIN    512     // input dim
#define KD     256     // NUM_CAPS * DIM_CAPS
#define NCAPS  16
#define EPS    1e-7f

#define ROWS_PER_BLK 32
#define NCHUNK (NN / ROWS_PER_BLK)   // 32 partial rows per batch
#define WCHUNK 64                    // W rows staged per pipeline step
#define NWCH   (DIN / WCHUNK)        // 8 chunks

// ---------------------------------------------------------------------------
// Kernel A (proven, unchanged): partial column sums. 512 blocks x 256 thr.
// Each block reads 32 rows (64 KB contiguous, float4, 16 loads in flight
// per thread) and emits one partial row P[blk][512].
// ---------------------------------------------------------------------------
__global__ __launch_bounds__(256) void colsum_partial(
    const float* __restrict__ in, float* __restrict__ P)
{
    __shared__ float4 sh[128];
    int blk = blockIdx.x;
    int t   = threadIdx.x;
    int par  = t >> 7;
    int col4 = t & 127;

    const float4* base = (const float4*)in
        + (size_t)blk * ROWS_PER_BLK * (DIN / 4);

    float4 acc = make_float4(0.f, 0.f, 0.f, 0.f);
    #pragma unroll
    for (int r = 0; r < ROWS_PER_BLK / 2; ++r) {
        float4 v = base[(size_t)(2 * r + par) * (DIN / 4) + col4];
        acc.x += v.x; acc.y += v.y; acc.z += v.z; acc.w += v.w;
    }
    if (par) sh[col4] = acc;
    __syncthreads();
    if (!par) {
        float4 o = sh[col4];
        acc.x += o.x; acc.y += o.y; acc.z += o.z; acc.w += o.w;
        ((float4*)P)[(size_t)blk * (DIN / 4) + col4] = acc;
    }
}

// ---------------------------------------------------------------------------
// Fused tail: 16 blocks (one per batch) x 1024 threads, launch_bounds(1024,4)
// so the allocator gets 128 VGPRs (R4's 20-VGPR starvation serialized loads).
//
//  1) P stage->regs: thread (g=t>>9, i=t&511) issues 16 INDEPENDENT
//     row-coalesced loads (one latency round), reduces in regs -> part[g][i],
//     xs[i] = part0+part1.
//  2) W dot, software-pipelined: 8 chunks of 64 rows (64 KB). Chunk c+1's
//     4 float4 loads/thread are issued while chunk c computes from LDS.
//     Register ping-pong uses two NAMED arrays + explicit pair-steps (all
//     static indexing -- runtime-indexed vector arrays go to scratch).
//     Thread (h=t>>8, d=t&255): acc += xs[c*64+h*16+ii] * wl[h*16+ii][d]
//     (xs: wave-uniform broadcast; wl: lanes->consecutive banks. no conflict)
//  3) reduce 4 h-partials, squash, write 16 identical k-copies (exact
//     routing degeneracy: softmax stays 1/16, update is k-constant).
// ---------------------------------------------------------------------------
__global__ __launch_bounds__(1024, 4) void tail_fused(
    const float* __restrict__ P, const float* __restrict__ W,
    float* __restrict__ out)
{
    __shared__ float wl[WCHUNK][KD];   // 64 KB, single buffer
    __shared__ float part[2][DIN];     //  4 KB
    __shared__ float xs[DIN];          //  2 KB
    __shared__ float red2[4][KD];      //  4 KB
    __shared__ float svs[KD];          //  1 KB
    __shared__ float red[KD];          //  1 KB

    const int b = blockIdx.x;
    const int t = threadIdx.x;
    const int d = t & 255;
    const int h = t >> 8;              // 0..3

    const float4* W4 = (const float4*)W;   // [DIN][KD/4]

    // Issue chunk-0 W loads first; their s_waitcnt lands in step 0's LDS
    // write, after the whole P phase has hidden the latency.
    float4 wvA[4], wvB[4];
    #pragma unroll
    for (int j = 0; j < 4; ++j)
        wvA[j] = W4[j * 1024 + t];

    // ---- Phase 1: P -> xs. 16 independent coalesced loads per thread.
    {
        const int i = t & 511;
        const int g = t >> 9;          // 0 or 1
        const float* p = P + ((size_t)b * NCHUNK + g * 16) * DIN + i;
        float a0 = 0.f;
        #pragma unroll
        for (int j = 0; j < 16; ++j) a0 += p[(size_t)j * DIN];
        part[g][i] = a0;
    }
    __syncthreads();
    if (t < DIN) xs[t] = part[0][t] + part[1][t];
    __syncthreads();

    // ---- Phase 2: pipelined W-dot.
    float acc = 0.f;

    auto wstep = [&](int c, float4 (&cur)[4], float4 (&nxt)[4]) {
        // stage chunk c (waits on cur's loads; prior trailing sync
        // guarantees everyone is done computing chunk c-1 from wl)
        #pragma unroll
        for (int j = 0; j < 4; ++j) {
            int idx  = j * 1024 + t;
            int row  = idx >> 6;       // 0..63
            int col4 = idx & 63;
            *(float4*)&wl[row][col4 * 4] = cur[j];
        }
        __syncthreads();
        // prefetch chunk c+1
        if (c + 1 < NWCH) {
            const float4* base = W4 + (size_t)(c + 1) * WCHUNK * (KD / 4);
            #pragma unroll
            for (int j = 0; j < 4; ++j)
                nxt[j] = base[j * 1024 + t];
        }
        // compute chunk c: 16 MACs from LDS
        #pragma unroll
        for (int ii = 0; ii < 16; ++ii)
            acc += xs[c * WCHUNK + h * 16 + ii] * wl[h * 16 + ii][d];
        __syncthreads();
    };

    #pragma unroll
    for (int cc = 0; cc < NWCH / 2; ++cc) {
        wstep(2 * cc,     wvA, wvB);
        wstep(2 * cc + 1, wvB, wvA);
    }

    // ---- Phase 3: reduce h-partials, squash, write.
    red2[h][d] = acc;
    __syncthreads();
    if (t < KD) {
        float sv = (red2[0][t] + red2[1][t] + red2[2][t] + red2[3][t])
                   * (1.0f / 16.0f);   // softmax c = 1/16 exactly
        svs[t] = sv;
        red[t] = sv * sv;
    }
    __syncthreads();
    for (int off = 128; off > 0; off >>= 1) {
        if (t < off) red[t] += red[t + off];
        __syncthreads();
    }
    const float sq    = red[0];
    const float scale = (sq / (1.0f + sq)) / sqrtf(sq + EPS);

    {
        const int kk = t >> 8;         // 0..3
        const float o = scale * svs[d];
        #pragma unroll
        for (int m = 0; m < 4; ++m)
            out[((size_t)b * NCAPS + (kk * 4 + m)) * KD + d] = o;
    }
}

extern "C" void kernel_launch(void* const* d_in, const int* in_sizes, int n_in,
                              void* d_out, int out_size, void* d_ws, size_t ws_size,
                              hipStream_t stream)
{
    const float* in = (const float*)d_in[0];  // [16,1024,512] f32
    const float* W  = (const float*)d_in[1];  // [512,256] f32
    float* out = (float*)d_out;               // [16,16,256] f32

    float* P = (float*)d_ws;                  // 512*512 f32 = 1 MB

    colsum_partial<<<BSZ * NCHUNK, 256, 0, stream>>>(in, P);
    tail_fused<<<BSZ, 1024, 0, stream>>>(P, W, out);
}

// Round 7
// 32.477 us; speedup vs baseline: 1.4987x; 1.4987x over previous
//
#include <hip/hip_runtime.h>

// Problem constants (fixed by the reference).
#define BSZ    16      // batch
#define NN     1024    // tokens per batch
#define DIN    512     // input dim
#define KD     256     // NUM_CAPS * DIM_CAPS
#define NCAPS  16
#define EPS    1e-7f

#define ROWS_PER_BLK 32
#define NCHUNK (NN / ROWS_PER_BLK)   // 32 blocks per batch
#define FXSCALE 34359738368.0        // 2^35 fixed-point scale

// ---------------------------------------------------------------------------
// Single kernel, 512 blocks x 1024 threads. NO fences, NO spinning.
//
// Phase A (all blocks; R3-validated code): colsum this block's 32 input rows
// (float4, coalesced, 4 independent loads/thread) -> 128 threads hold the
// block partial xs_blk as float4.
//
// Cross-block reduction: xs_blk is quantized to int64 fixed point (2^35) and
// atomicAdd'ed into XS[b][i]. Integer adds commute -> the final XS bits are
// IDENTICAL regardless of block order => deterministic. Device-scope atomics
// are performed at the coherent point: no cache fences needed (R3's 512
// __threadfence()'s = buffer_wbl2 storms cost 45 us; atomics avoid that).
// Returns are consumed (asm) so __syncthreads()' vmcnt(0) drain proves the
// adds are globally performed before t0 bumps cnt[b]. Last block (old==31)
// runs the tail; everyone else exits -- no co-residency assumption.
//
// Tail (one block per batch, overlapped with other batches' phase A):
// read XS via atomic-reads (coherent by construction), decode to float,
// then H[d] = sum_i xs[i]*W[i][d] with NO LDS staging and NO barriers in
// the loop: h-split (4 x 128-deep), unroll 16 -> 16 coalesced 1 KB W-row
// loads in flight per wave, 16 waves (R6 lesson: barriered LDS chunking
// serializes at full memory latency per chunk). Then squash + 16 identical
// k-copies (exact routing degeneracy: softmax stays 1/16, agreement update
// is k-constant -- validated R1-R6, absmax 0).
// ---------------------------------------------------------------------------
__global__ __launch_bounds__(1024) void caps_onekernel(
    const float* __restrict__ in, const float* __restrict__ W,
    unsigned long long* __restrict__ XS, unsigned* __restrict__ cnt,
    float* __restrict__ out)
{
    __shared__ float4 shA[8][128];     // 16 KB
    __shared__ float  xs[DIN];         //  2 KB
    __shared__ float  red2[4][KD];     //  4 KB
    __shared__ float  svs[KD];         //  1 KB
    __shared__ float  red[KD];         //  1 KB
    __shared__ int    sh_last;

    const int blk = blockIdx.x;
    const int b   = blk >> 5;          // batch = blk / NCHUNK
    const int t   = threadIdx.x;

    // ---- Phase A: colsum 32 rows x 512 cols (R3-validated).
    {
        const int col4 = t & 127;
        const int rg   = t >> 7;       // 0..7
        const float4* base = (const float4*)in
            + (size_t)blk * ROWS_PER_BLK * (DIN / 4);
        float4 acc = make_float4(0.f, 0.f, 0.f, 0.f);
        #pragma unroll
        for (int j = 0; j < 4; ++j) {
            float4 v = base[(size_t)(rg + 8 * j) * (DIN / 4) + col4];
            acc.x += v.x; acc.y += v.y; acc.z += v.z; acc.w += v.w;
        }
        shA[rg][col4] = acc;
    }
    __syncthreads();
    if (t < 128) {
        float4 a = shA[0][t];
        #pragma unroll
        for (int g = 1; g < 8; ++g) {
            float4 v = shA[g][t];
            a.x += v.x; a.y += v.y; a.z += v.z; a.w += v.w;
        }
        // Quantize to int64 fixed point and accumulate (4 adds in flight).
        unsigned long long* dst = XS + (size_t)b * DIN + 4 * t;
        unsigned long long q0 = (unsigned long long)(long long)llrint((double)a.x * FXSCALE);
        unsigned long long q1 = (unsigned long long)(long long)llrint((double)a.y * FXSCALE);
        unsigned long long q2 = (unsigned long long)(long long)llrint((double)a.z * FXSCALE);
        unsigned long long q3 = (unsigned long long)(long long)llrint((double)a.w * FXSCALE);
        unsigned long long o0 = atomicAdd(dst + 0, q0);
        unsigned long long o1 = atomicAdd(dst + 1, q1);
        unsigned long long o2 = atomicAdd(dst + 2, q2);
        unsigned long long o3 = atomicAdd(dst + 3, q3);
        // Keep the returns live: forces the waitcnt that proves completion.
        asm volatile("" :: "v"((unsigned)o0), "v"((unsigned)o1),
                           "v"((unsigned)o2), "v"((unsigned)o3));
    }
    __syncthreads();                   // all waves' atomics drained (vmcnt 0)

    if (t == 0) {
        unsigned old = atomicAdd(&cnt[b], 1u);
        sh_last = (old == NCHUNK - 1);
    }
    __syncthreads();
    if (!sh_last) return;

    // ---- Tail: unique last block of batch b.
    // Coherent read-back of XS (atomic fetch-add of 0), decode fixed point.
    if (t < DIN) {
        unsigned long long v = atomicAdd(&XS[(size_t)b * DIN + t], 0ULL);
        xs[t] = (float)((double)(long long)v * (1.0 / FXSCALE));
    }
    __syncthreads();

    // H[d] = sum_i xs[i] * W[i][d]; no LDS staging, no barriers in loop.
    {
        const int d = t & 255;
        const int h = t >> 8;          // 0..3
        const float* w = W + (size_t)(h * 128) * KD + d;
        float acc = 0.f;
        #pragma unroll 16
        for (int ii = 0; ii < 128; ++ii)
            acc += xs[h * 128 + ii] * w[(size_t)ii * KD];
        red2[h][d] = acc;
    }
    __syncthreads();
    if (t < KD) {
        float sv = (red2[0][t] + red2[1][t] + red2[2][t] + red2[3][t])
                   * (1.0f / 16.0f);   // softmax c = 1/16 exactly
        svs[t] = sv;
        red[t] = sv * sv;
    }
    __syncthreads();
    for (int off = 128; off > 0; off >>= 1) {
        if (t < off) red[t] += red[t + off];
        __syncthreads();
    }
    const float sq    = red[0];
    const float scale = (sq / (1.0f + sq)) / sqrtf(sq + EPS);

    {
        const int d  = t & 255;
        const int kk = t >> 8;         // 0..3
        const float o = scale * svs[d];
        #pragma unroll
        for (int m = 0; m < 4; ++m)
            out[((size_t)b * NCAPS + (kk * 4 + m)) * KD + d] = o;
    }
}

extern "C" void kernel_launch(void* const* d_in, const int* in_sizes, int n_in,
                              void* d_out, int out_size, void* d_ws, size_t ws_size,
                              hipStream_t stream)
{
    const float* in = (const float*)d_in[0];  // [16,1024,512] f32
    const float* W  = (const float*)d_in[1];  // [512,256] f32
    float* out = (float*)d_out;               // [16,16,256] f32

    unsigned long long* XS = (unsigned long long*)d_ws;       // 16*512 u64 = 64 KB
    unsigned* cnt = (unsigned*)((char*)d_ws + (size_t)BSZ * DIN * 8); // 16 u32

    // XS and cnt must be zero at kernel start on EVERY replay (d_ws is
    // poisoned once, never re-poisoned). Captured into the graph.
    hipMemsetAsync(d_ws, 0, (size_t)BSZ * DIN * 8 + BSZ * sizeof(unsigned),
                   stream);

    caps_onekernel<<<BSZ * NCHUNK, 1024, 0, stream>>>(in, W, XS, cnt, out);
}

// Round 8
// 19.358 us; speedup vs baseline: 2.5143x; 1.6777x over previous
//
#include <hip/hip_runtime.h>

// Problem constants (fixed by the reference).
#define BSZ    16      // batch
#define NN     1024    // tokens per batch
#define DIN    512     // input dim
#define KD     256     // NUM_CAPS * DIM_CAPS
#define NCAPS  16
#define EPS    1e-7f

#define ROWS_PER_BLK 32
#define NCHUNK (NN / ROWS_PER_BLK)   // 32 partial rows per batch

// ---------------------------------------------------------------------------
// Kernel A (proven, unchanged since R2): partial column sums.
// 512 blocks x 256 threads; each block reads 32 rows (64 KB contiguous,
// float4, 16 loads in flight per thread) and emits one partial row P[blk].
// ---------------------------------------------------------------------------
__global__ __launch_bounds__(256) void colsum_partial(
    const float* __restrict__ in, float* __restrict__ P)
{
    __shared__ float4 sh[128];
    int blk = blockIdx.x;
    int t   = threadIdx.x;
    int par  = t >> 7;
    int col4 = t & 127;

    const float4* base = (const float4*)in
        + (size_t)blk * ROWS_PER_BLK * (DIN / 4);

    float4 acc = make_float4(0.f, 0.f, 0.f, 0.f);
    #pragma unroll
    for (int r = 0; r < ROWS_PER_BLK / 2; ++r) {
        float4 v = base[(size_t)(2 * r + par) * (DIN / 4) + col4];
        acc.x += v.x; acc.y += v.y; acc.z += v.z; acc.w += v.w;
    }
    if (par) sh[col4] = acc;
    __syncthreads();
    if (!par) {
        float4 o = sh[col4];
        acc.x += o.x; acc.y += o.y; acc.z += o.z; acc.w += o.w;
        ((float4*)P)[(size_t)blk * (DIN / 4) + col4] = acc;
    }
}

// ---------------------------------------------------------------------------
// Fused tail (B+C): 16 blocks (one per batch) x 1024 threads.
// Failure-mode avoidance:
//  - R4 (VGPR=20, ~2 loads in flight, serial 900-cyc chains): ILP is FORCED
//    by named statically-indexed register batches wv0/wv of 32 loads each;
//    __launch_bounds__(1024,4) gives the allocator 512-VGPR headroom.
//  - R6 (barriered LDS chunk pipeline serialized on vmcnt per chunk): the
//    W-dot reads straight from L2 -- NO LDS staging, NO barriers in the loop.
//  - W round 0 is issued BEFORE the P phase so its latency hides under the
//    P reduce.
// Layout: thread (h=t>>8, d=t&255); H[d] = sum over i of xs[i]*W[i][d],
// h-split 4 x 128; per round a wave's 64 lanes read 64 consecutive floats
// of one W row (coalesced 256 B x 4 rows in flight per instruction batch).
// Then reduce h-partials, squash, write 16 identical k-copies (exact
// routing degeneracy: softmax stays 1/16; validated R1-R7, absmax <= 2e-5).
// ---------------------------------------------------------------------------
__global__ __launch_bounds__(1024, 4) void tail_bc(
    const float* __restrict__ P, const float* __restrict__ W,
    float* __restrict__ out)
{
    __shared__ float part[2][DIN];     // 4 KB
    __shared__ float xs[DIN];          // 2 KB
    __shared__ float red2[4][KD];      // 4 KB
    __shared__ float svs[KD];          // 1 KB
    __shared__ float red[KD];          // 1 KB

    const int b = blockIdx.x;
    const int t = threadIdx.x;
    const int d = t & 255;
    const int h = t >> 8;              // 0..3

    const float* w = W + (size_t)(h * 128) * KD + d;

    // W round 0: 32 independent coalesced loads, in flight across phase 1.
    float wv0[32];
    #pragma unroll
    for (int j = 0; j < 32; ++j) wv0[j] = w[(size_t)j * KD];

    // ---- Phase 1: P -> xs. 16 independent coalesced row loads per thread.
    {
        const int i = t & 511;
        const int g = t >> 9;          // 0 or 1
        const float* p = P + ((size_t)b * NCHUNK + g * 16) * DIN + i;
        float a0 = 0.f;
        #pragma unroll
        for (int j = 0; j < 16; ++j) a0 += p[(size_t)j * DIN];
        part[g][i] = a0;
    }
    __syncthreads();
    if (t < DIN) xs[t] = part[0][t] + part[1][t];
    __syncthreads();

    // ---- Phase 2: 128-deep dot, 4 rounds x 32 batched loads, no barriers.
    // Per-thread accumulation order is ascending i (matches validated tail).
    float acc = 0.f;
    #pragma unroll
    for (int j = 0; j < 32; ++j)
        acc += xs[h * 128 + j] * wv0[j];
    #pragma unroll
    for (int r = 1; r < 4; ++r) {
        float wv[32];
        #pragma unroll
        for (int j = 0; j < 32; ++j)
            wv[j] = w[(size_t)(r * 32 + j) * KD];
        #pragma unroll
        for (int j = 0; j < 32; ++j)
            acc += xs[h * 128 + r * 32 + j] * wv[j];
    }
    red2[h][d] = acc;
    __syncthreads();

    // ---- Phase 3: reduce h-partials, squash, write.
    if (t < KD) {
        float sv = (red2[0][t] + red2[1][t] + red2[2][t] + red2[3][t])
                   * (1.0f / 16.0f);   // softmax c = 1/16 exactly
        svs[t] = sv;
        red[t] = sv * sv;
    }
    __syncthreads();
    for (int off = 128; off > 0; off >>= 1) {
        if (t < off) red[t] += red[t + off];
        __syncthreads();
    }
    const float sq    = red[0];
    const float scale = (sq / (1.0f + sq)) / sqrtf(sq + EPS);

    {
        const int kk = t >> 8;         // 0..3
        const float o = scale * svs[d];
        #pragma unroll
        for (int m = 0; m < 4; ++m)
            out[((size_t)b * NCAPS + (kk * 4 + m)) * KD + d] = o;
    }
}

extern "C" void kernel_launch(void* const* d_in, const int* in_sizes, int n_in,
                              void* d_out, int out_size, void* d_ws, size_t ws_size,
                              hipStream_t stream)
{
    const float* in = (const float*)d_in[0];  // [16,1024,512] f32
    const float* W  = (const float*)d_in[1];  // [512,256] f32
    float* out = (float*)d_out;               // [16,16,256] f32

    float* P = (float*)d_ws;                  // 512*512 f32 = 1 MB

    colsum_partial<<<BSZ * NCHUNK, 256, 0, stream>>>(in, P);
    tail_bc<<<BSZ, 1024, 0, stream>>>(P, W, out);
}

// Round 9
// 16.261 us; speedup vs baseline: 2.9932x; 1.1904x over previous
//
#include <hip/hip_runtime.h>

// Problem constants (fixed by the reference).
#define BSZ    16      // batch
#define NN     1024    // tokens per batch
#define DIN    512     // input dim
#define KD     256     // NUM_CAPS * DIM_CAPS
#define NCAPS  16
#define EPS    1e-7f

#define ROWS_PER_BLK 32
#define NCHUNK (NN / ROWS_PER_BLK)   // 32 partial rows per batch
#define NSPLIT 16                    // i-splits for the tiny GEMM
#define ICHUNK (DIN / NSPLIT)        // 32

// ---------------------------------------------------------------------------
// Kernel A (byte-identical to the proven 15.27 µs R5 version): partial column
// sums. 512 blocks x 256 threads; each block reads 32 rows (64 KB contiguous,
// float4, 16 loads in flight/thread) and emits one partial row P[blk][512].
// ---------------------------------------------------------------------------
__global__ __launch_bounds__(256) void colsum_partial(
    const float* __restrict__ in, float* __restrict__ P)
{
    __shared__ float4 sh[128];
    int blk = blockIdx.x;
    int t   = threadIdx.x;
    int par  = t >> 7;
    int col4 = t & 127;

    const float4* base = (const float4*)in
        + (size_t)blk * ROWS_PER_BLK * (DIN / 4);

    float4 acc = make_float4(0.f, 0.f, 0.f, 0.f);
    #pragma unroll
    for (int r = 0; r < ROWS_PER_BLK / 2; ++r) {
        float4 v = base[(size_t)(2 * r + par) * (DIN / 4) + col4];
        acc.x += v.x; acc.y += v.y; acc.z += v.z; acc.w += v.w;
    }
    if (par) sh[col4] = acc;
    __syncthreads();
    if (!par) {
        float4 o = sh[col4];
        acc.x += o.x; acc.y += o.y; acc.z += o.z; acc.w += o.w;
        ((float4*)P)[(size_t)blk * (DIN / 4) + col4] = acc;
    }
}

// ---------------------------------------------------------------------------
// Kernel B' = R5's partial_gemm (validated, absmax 0.0) + fused C via
// last-block election. 256 blocks (b,s) x 256 threads -- keeps the wide TLP
// that made R5's B fast (R4/R6/R8: any 16-block tail shape costs ~11 us).
//
// Publication protocol (numerically validated in R7): each thread
// atomicExch's its partial into P2 (device-scope, coherent point); return
// consumed via asm so __syncthreads()'s vmcnt(0) drain proves global
// completion before t0 bumps cnt[b]. Election: old%16==15 -> winner. cnt is
// NEVER reset: it grows by 16 per batch per call, and any 16 consecutive
// values contain exactly one o%16==15 -> works from any initial value
// (poison, garbage) with no in-graph memset (R7's memset node cost).
// Winner reads all 16 partials back via atomicAdd(p,0) (coherent point --
// immune to stale per-XCD L2 lines from previous replays), reduces in fixed
// s-order (deterministic output regardless of which block wins), applies
// squash, writes 16 identical k-copies (exact routing degeneracy: softmax
// stays exactly 1/16; agreement update is k-constant -- validated R1-R8).
// ---------------------------------------------------------------------------
__global__ __launch_bounds__(256) void partial_gemm_fused(
    const float* __restrict__ P, const float* __restrict__ W,
    unsigned* __restrict__ P2u, unsigned* __restrict__ cnt,
    float* __restrict__ out)
{
    __shared__ float wl[ICHUNK][KD];   // 32 KB
    __shared__ float pt[ICHUNK][33];   // P tile, padded
    __shared__ float pr[8][33];        // group partials
    __shared__ float xs[ICHUNK];
    __shared__ float svs[KD];
    __shared__ float red[KD];
    __shared__ int   sh_win;

    const int b  = blockIdx.x >> 4;
    const int s  = blockIdx.x & (NSPLIT - 1);
    const int t  = threadIdx.x;
    const int i0 = s * ICHUNK;

    // ---- B phase (identical math to R5's partial_gemm) ----
    // Issue ALL global loads first (9 independent float4 loads per thread).
    const float4* W4 = (const float4*)W + (size_t)i0 * (KD / 4);
    float4 wv[8];
    #pragma unroll
    for (int k = 0; k < 8; ++k)
        wv[k] = W4[k * 256 + t];               // 2048 float4 = 32 rows x 64

    const int c = t >> 3;                      // P row 0..31
    const int q = t & 7;                       // float4 col within chunk
    float4 pv = ((const float4*)P)[((size_t)b * NCHUNK + c) * (DIN / 4)
                                   + (i0 / 4) + q];

    #pragma unroll
    for (int k = 0; k < 8; ++k) {
        int idx  = k * 256 + t;
        int row  = idx >> 6;                   // 0..31
        int col4 = idx & 63;
        *(float4*)&wl[row][col4 * 4] = wv[k];
    }
    pt[c][q * 4 + 0] = pv.x;
    pt[c][q * 4 + 1] = pv.y;
    pt[c][q * 4 + 2] = pv.z;
    pt[c][q * 4 + 3] = pv.w;
    __syncthreads();

    {
        const int g = t >> 5;                  // 0..7
        const int i = t & 31;
        pr[g][i] = pt[g * 4 + 0][i] + pt[g * 4 + 1][i]
                 + pt[g * 4 + 2][i] + pt[g * 4 + 3][i];
    }
    __syncthreads();
    if (t < ICHUNK)
        xs[t] = pr[0][t] + pr[1][t] + pr[2][t] + pr[3][t]
              + pr[4][t] + pr[5][t] + pr[6][t] + pr[7][t];
    __syncthreads();

    float acc = 0.f;
    #pragma unroll
    for (int i = 0; i < ICHUNK; ++i)
        acc += xs[i] * wl[i][t];

    // ---- Publish + elect ----
    {
        unsigned old = atomicExch(&P2u[(((size_t)b * NSPLIT + s) << 8) + t],
                                  __float_as_uint(acc));
        asm volatile("" :: "v"(old));          // keep return live
    }
    __syncthreads();                           // drains vmcnt(0): exch done
    if (t == 0) {
        unsigned o = atomicAdd(&cnt[b], 1u);
        sh_win = ((o & 15u) == 15u);           // exactly one winner per call
    }
    __syncthreads();
    if (!sh_win) return;

    // ---- C phase (winner only; fixed s-order => deterministic) ----
    float sum = 0.f;
    #pragma unroll
    for (int s2 = 0; s2 < NSPLIT; ++s2) {      // 16 independent atomic reads
        unsigned u = atomicAdd(&P2u[(((size_t)b * NSPLIT + s2) << 8) + t], 0u);
        sum += __uint_as_float(u);
    }
    const float sv = sum * (1.0f / 16.0f);     // softmax c = 1/16 exactly
    svs[t] = sv;
    red[t] = sv * sv;
    __syncthreads();
    for (int off = 128; off > 0; off >>= 1) {
        if (t < off) red[t] += red[t + off];
        __syncthreads();
    }
    const float sq    = red[0];
    const float scale = (sq / (1.0f + sq)) / sqrtf(sq + EPS);
    const float o     = scale * svs[t];

    #pragma unroll
    for (int k = 0; k < NCAPS; ++k)
        out[((size_t)b * NCAPS + k) * KD + t] = o;
}

extern "C" void kernel_launch(void* const* d_in, const int* in_sizes, int n_in,
                              void* d_out, int out_size, void* d_ws, size_t ws_size,
                              hipStream_t stream)
{
    const float* in = (const float*)d_in[0];  // [16,1024,512] f32
    const float* W  = (const float*)d_in[1];  // [512,256] f32
    float* out = (float*)d_out;               // [16,16,256] f32

    float*    P   = (float*)d_ws;                         // 1 MB
    unsigned* P2u = (unsigned*)(P + (size_t)BSZ * NCHUNK * DIN);   // 256 KB
    unsigned* cnt = P2u + (size_t)BSZ * NSPLIT * KD;      // 16 u32, never reset

    colsum_partial<<<BSZ * NCHUNK, 256, 0, stream>>>(in, P);
    partial_gemm_fused<<<BSZ * NSPLIT, 256, 0, stream>>>(P, W, P2u, cnt, out);
}

// Round 10
// 15.099 us; speedup vs baseline: 3.2235x; 1.0770x over previous
//
#include <hip/hip_runtime.h>

// Problem constants (fixed by the reference).
#define BSZ    16      // batch
#define NN     1024    // tokens per batch
#define DIN    512     // input dim
#define KD     256     // NUM_CAPS * DIM_CAPS
#define NCAPS  16
#define EPS    1e-7f

#define ROWS_PER_BLK 32
#define NCHUNK (NN / ROWS_PER_BLK)   // 32 partial rows per batch
#define NSPLIT 16                    // i-splits for the tiny GEMM
#define ICHUNK (DIN / NSPLIT)        // 32

// ---------------------------------------------------------------------------
// PROVEN best configuration (R5: 15.27 us, absmax 0.0). Structure ledger:
//   3 dispatches = 15.27/15.39 | 2 = 16.26/19.36/19.43/48.67 | 1 = 32.5/60.7
// Cross-block handoff inside a kernel always costs more than a boundary:
//   per-block __threadfence (buffer_wbl2) +45us; in-graph memset ~10us;
//   atomic publish/elect +1-3us; ANY 16-block tail shape ~12us (R4==R8:
//   internal structure irrelevant). Kernel-boundary coherence is cheapest.
//
// Math: routing is exactly degenerate (input_hat independent of k) =>
// softmax stays exactly 1/16, agreement update is k-constant =>
// out[b,k,:] = squash((1/16) * (sum_n inputs[b,n,:]) @ W) for every k.
// ---------------------------------------------------------------------------

// Kernel A: partial column sums. 512 blocks x 256 threads; each block reads
// 32 rows (64 KB contiguous, float4, 16 loads in flight/thread) and emits
// one partial row P[blk][512].
__global__ __launch_bounds__(256) void colsum_partial(
    const float* __restrict__ in, float* __restrict__ P)
{
    __shared__ float4 sh[128];
    int blk = blockIdx.x;
    int t   = threadIdx.x;
    int par  = t >> 7;
    int col4 = t & 127;

    const float4* base = (const float4*)in
        + (size_t)blk * ROWS_PER_BLK * (DIN / 4);

    float4 acc = make_float4(0.f, 0.f, 0.f, 0.f);
    #pragma unroll
    for (int r = 0; r < ROWS_PER_BLK / 2; ++r) {
        float4 v = base[(size_t)(2 * r + par) * (DIN / 4) + col4];
        acc.x += v.x; acc.y += v.y; acc.z += v.z; acc.w += v.w;
    }
    if (par) sh[col4] = acc;
    __syncthreads();
    if (!par) {
        float4 o = sh[col4];
        acc.x += o.x; acc.y += o.y; acc.z += o.z; acc.w += o.w;
        ((float4*)P)[(size_t)blk * (DIN / 4) + col4] = acc;
    }
}

// Kernel B: partial tiny-GEMM, 256 blocks (b,s) x 256 threads. All global
// reads are single-round independent float4 loads; dot runs from LDS.
__global__ __launch_bounds__(256) void partial_gemm(
    const float* __restrict__ P, const float* __restrict__ W,
    float* __restrict__ P2)
{
    __shared__ float wl[ICHUNK][KD];   // 32 KB
    __shared__ float pt[ICHUNK][33];   // P tile, padded (col-sum over rows)
    __shared__ float pr[8][33];        // group partials
    __shared__ float xs[ICHUNK];

    const int b  = blockIdx.x >> 4;
    const int s  = blockIdx.x & (NSPLIT - 1);
    const int t  = threadIdx.x;
    const int i0 = s * ICHUNK;

    // Issue ALL global loads first (9 independent float4 loads per thread).
    const float4* W4 = (const float4*)W + (size_t)i0 * (KD / 4);
    float4 wv[8];
    #pragma unroll
    for (int k = 0; k < 8; ++k)
        wv[k] = W4[k * 256 + t];               // 2048 float4 = 32 rows x 64

    const int c = t >> 3;                      // P row 0..31
    const int q = t & 7;                       // float4 col within chunk
    float4 pv = ((const float4*)P)[((size_t)b * NCHUNK + c) * (DIN / 4)
                                   + (i0 / 4) + q];

    // LDS writes (wait on the loads, all in one round).
    #pragma unroll
    for (int k = 0; k < 8; ++k) {
        int idx  = k * 256 + t;
        int row  = idx >> 6;                   // 0..31
        int col4 = idx & 63;
        *(float4*)&wl[row][col4 * 4] = wv[k];  // contiguous b128, no conflict
    }
    pt[c][q * 4 + 0] = pv.x;
    pt[c][q * 4 + 1] = pv.y;
    pt[c][q * 4 + 2] = pv.z;
    pt[c][q * 4 + 3] = pv.w;
    __syncthreads();

    // Column-sum pt over c: 8 groups x 4 rows, then 8.
    {
        const int g = t >> 5;                  // 0..7
        const int i = t & 31;
        pr[g][i] = pt[g * 4 + 0][i] + pt[g * 4 + 1][i]
                 + pt[g * 4 + 2][i] + pt[g * 4 + 3][i];
    }
    __syncthreads();
    if (t < ICHUNK)
        xs[t] = pr[0][t] + pr[1][t] + pr[2][t] + pr[3][t]
              + pr[4][t] + pr[5][t] + pr[6][t] + pr[7][t];
    __syncthreads();

    // 32-deep dot entirely from LDS.
    float acc = 0.f;
    #pragma unroll
    for (int i = 0; i < ICHUNK; ++i)
        acc += xs[i] * wl[i][t];
    P2[((size_t)b * NSPLIT + s) * KD + t] = acc;
}

// Kernel C: reduce NSPLIT partials, squash, write 16 identical k-copies.
// grid = 16 blocks, 256 threads. P2 tile (16 KB) staged in ONE float4 round.
__global__ __launch_bounds__(256) void squash_out(
    const float* __restrict__ P2, float* __restrict__ out)
{
    __shared__ float part[4][KD];
    __shared__ float svs[KD];
    __shared__ float red[KD];

    const int b = blockIdx.x;
    const int t = threadIdx.x;
    const int g  = t >> 6;                     // 0..3
    const int d4 = t & 63;                     // float4 col 0..63

    const float4* P24 = (const float4*)P2 + (size_t)b * NSPLIT * (KD / 4);
    float4 a = make_float4(0.f, 0.f, 0.f, 0.f);
    #pragma unroll
    for (int j = 0; j < 4; ++j) {              // 4 independent loads
        float4 v = P24[(size_t)(g * 4 + j) * (KD / 4) + d4];
        a.x += v.x; a.y += v.y; a.z += v.z; a.w += v.w;
    }
    *(float4*)&part[g][d4 * 4] = a;
    __syncthreads();

    const float sv = (part[0][t] + part[1][t] + part[2][t] + part[3][t])
                     * (1.0f / 16.0f);         // softmax c = 1/16 exactly
    svs[t] = sv;
    red[t] = sv * sv;
    __syncthreads();
    for (int off = 128; off > 0; off >>= 1) {
        if (t < off) red[t] += red[t + off];
        __syncthreads();
    }
    const float sq    = red[0];
    const float scale = (sq / (1.0f + sq)) / sqrtf(sq + EPS);
    const float o     = scale * svs[t];

    #pragma unroll
    for (int k = 0; k < NCAPS; ++k)
        out[((size_t)b * NCAPS + k) * KD + t] = o;
}

extern "C" void kernel_launch(void* const* d_in, const int* in_sizes, int n_in,
                              void* d_out, int out_size, void* d_ws, size_t ws_size,
                              hipStream_t stream)
{
    const float* in = (const float*)d_in[0];  // [16,1024,512] f32
    const float* W  = (const float*)d_in[1];  // [512,256] f32
    float* out = (float*)d_out;               // [16,16,256] f32

    float* P  = (float*)d_ws;                       // 512*512 f32 = 1 MB
    float* P2 = P + (size_t)BSZ * NCHUNK * DIN;     // 16*16*256 f32 = 256 KB

    colsum_partial<<<BSZ * NCHUNK, 256, 0, stream>>>(in, P);
    partial_gemm<<<BSZ * NSPLIT, 256, 0, stream>>>(P, W, P2);
    squash_out<<<BSZ, 256, 0, stream>>>(P2, out);
}

// Round 11
// 12.965 us; speedup vs baseline: 3.7542x; 1.1646x over previous
//
#include <hip/hip_runtime.h>

// Problem constants (fixed by the reference).
#define BSZ    16      // batch
#define NN     1024    // tokens per batch
#define DIN    512     // input dim
#define KD     256     // NUM_CAPS * DIM_CAPS
#define NCAPS  16
#define EPS    1e-7f

#define NSPLIT  16                   // column splits (32 cols each)
#define ICHUNK  (DIN / NSPLIT)       // 32
#define NHALF   2                    // row halves (512 rows each)
#define NPART   (NSPLIT * NHALF)     // 32 partials per (b,d)

// ---------------------------------------------------------------------------
// Fused A+B: grid = 512 blocks (b, s, half) x 256 threads -- SAME streaming
// shape as the proven kernel A (8 waves/CU), but no P roundtrip and one
// fewer dispatch. No cross-block handoff (the R3/R7/R9 lesson: fences,
// in-graph memsets, and atomic publication all cost more than a boundary).
//
// Block (b,s,half): col-sums input[b][half*512 .. +512)[32s .. 32s+32)
// directly (each row segment = 128 B = exactly one aligned cache line; zero
// over-fetch; float4 = 16 B/lane), reduces via LDS to xs[32], then computes
// the 32-deep dot with the LDS-staged W chunk:
//   P2[b][s*2+half][d] = sum_i xs[i] * W[32s+i][d]
// Exact-degeneracy math (validated R1-R10): out = squash(H/16), H = colsum@W.
// ---------------------------------------------------------------------------
__global__ __launch_bounds__(256, 2) void colsum_gemm(
    const float* __restrict__ in, const float* __restrict__ W,
    float* __restrict__ P2)
{
    __shared__ float  wl[ICHUNK][KD];    // 32 KB   W chunk
    __shared__ float4 shp[32][8];        //  4 KB   per-rowgroup col partials
    __shared__ float4 pr[8][8];          //  1 KB
    __shared__ float  xs[ICHUNK];        // 128 B

    const int blk  = blockIdx.x;
    const int b    = blk >> 5;           // batch
    const int r5   = blk & 31;           // s*2 + half
    const int s    = r5 >> 1;
    const int half = r5 & 1;
    const int t    = threadIdx.x;

    // ---- Stage W chunk: 8 independent float4 loads (issued first).
    const float4* W4 = (const float4*)W + (size_t)(s * ICHUNK) * (KD / 4);
    float4 wv[8];
    #pragma unroll
    for (int k = 0; k < 8; ++k)
        wv[k] = W4[k * 256 + t];         // 2048 float4 = 32 rows x 64

    // ---- Col-sum 512 rows x 32 cols. Thread (rg = t>>3, c4 = t&7):
    // 16 independent float4 loads at row stride 32.
    {
        const int rg = t >> 3;           // 0..31
        const int c4 = t & 7;            // float4 col within chunk
        const float4* base = (const float4*)in
            + ((size_t)(b * NN + half * 512) * (DIN / 4))
            + (size_t)s * (ICHUNK / 4) + c4;
        float4 a = make_float4(0.f, 0.f, 0.f, 0.f);
        #pragma unroll
        for (int j = 0; j < 16; ++j) {
            float4 v = base[(size_t)(rg + 32 * j) * (DIN / 4)];
            a.x += v.x; a.y += v.y; a.z += v.z; a.w += v.w;
        }
        shp[rg][c4] = a;
    }

    // ---- LDS-write W chunk (waits the W loads; one round).
    #pragma unroll
    for (int k = 0; k < 8; ++k) {
        int idx  = k * 256 + t;
        int row  = idx >> 6;             // 0..31
        int col4 = idx & 63;
        *(float4*)&wl[row][col4 * 4] = wv[k];
    }
    __syncthreads();

    // ---- Reduce 32 rowgroups -> xs[32] (fixed order: 4-tree then 8).
    if (t < 64) {
        const int rg2 = t >> 3;          // 0..7
        const int c4  = t & 7;
        float4 a = shp[rg2 * 4 + 0][c4];
        #pragma unroll
        for (int u = 1; u < 4; ++u) {
            float4 v = shp[rg2 * 4 + u][c4];
            a.x += v.x; a.y += v.y; a.z += v.z; a.w += v.w;
        }
        pr[rg2][c4] = a;
    }
    __syncthreads();
    if (t < 8) {
        float4 a = pr[0][t];
        #pragma unroll
        for (int u = 1; u < 8; ++u) {
            float4 v = pr[u][t];
            a.x += v.x; a.y += v.y; a.z += v.z; a.w += v.w;
        }
        *(float4*)&xs[t * 4] = a;
    }
    __syncthreads();

    // ---- 32-deep dot entirely from LDS; write partial.
    float acc = 0.f;
    #pragma unroll
    for (int i = 0; i < ICHUNK; ++i)
        acc += xs[i] * wl[i][t];
    P2[((size_t)b * NPART + r5) * KD + t] = acc;
}

// ---------------------------------------------------------------------------
// Kernel C: reduce NPART=32 partials, squash, write 16 identical k-copies.
// grid = 16 blocks x 256 threads; 32 KB P2 tile staged in ONE float4 round
// (8 independent loads/thread), fixed-order reduce => deterministic.
// ---------------------------------------------------------------------------
__global__ __launch_bounds__(256) void squash_out(
    const float* __restrict__ P2, float* __restrict__ out)
{
    __shared__ float part[4][KD];
    __shared__ float svs[KD];
    __shared__ float red[KD];

    const int b = blockIdx.x;
    const int t = threadIdx.x;
    const int g  = t >> 6;                     // 0..3 (8 rows each)
    const int d4 = t & 63;                     // float4 col 0..63

    const float4* P24 = (const float4*)P2 + (size_t)b * NPART * (KD / 4);
    float4 a = make_float4(0.f, 0.f, 0.f, 0.f);
    #pragma unroll
    for (int j = 0; j < 8; ++j) {              // 8 independent loads
        float4 v = P24[(size_t)(g * 8 + j) * (KD / 4) + d4];
        a.x += v.x; a.y += v.y; a.z += v.z; a.w += v.w;
    }
    *(float4*)&part[g][d4 * 4] = a;
    __syncthreads();

    const float sv = (part[0][t] + part[1][t] + part[2][t] + part[3][t])
                     * (1.0f / 16.0f);         // softmax c = 1/16 exactly
    svs[t] = sv;
    red[t] = sv * sv;
    __syncthreads();
    for (int off = 128; off > 0; off >>= 1) {
        if (t < off) red[t] += red[t + off];
        __syncthreads();
    }
    const float sq    = red[0];
    const float scale = (sq / (1.0f + sq)) / sqrtf(sq + EPS);
    const float o     = scale * svs[t];

    #pragma unroll
    for (int k = 0; k < NCAPS; ++k)
        out[((size_t)b * NCAPS + k) * KD + t] = o;
}

extern "C" void kernel_launch(void* const* d_in, const int* in_sizes, int n_in,
                              void* d_out, int out_size, void* d_ws, size_t ws_size,
                              hipStream_t stream)
{
    const float* in = (const float*)d_in[0];  // [16,1024,512] f32
    const float* W  = (const float*)d_in[1];  // [512,256] f32
    float* out = (float*)d_out;               // [16,16,256] f32

    float* P2 = (float*)d_ws;                 // 16*32*256 f32 = 512 KB

    colsum_gemm<<<BSZ * NPART, 256, 0, stream>>>(in, W, P2);
    squash_out<<<BSZ, 256, 0, stream>>>(P2, out);
}